// Round 1
// baseline (1088.313 us; speedup 1.0000x reference)
//
#include <hip/hip_runtime.h>
#include <math.h>

// Problem sizes
constexpr int NPTS = 8192;
constexpr int DIM  = 512;
constexpr int KC   = 8;    // clusters
constexpr int NNB  = 5;    // neighbors

// Output layout (floats)
constexpr int OFF_ENC    = 0;
constexpr int OFF_ASSIGN = NPTS * 32;                 // 262144
constexpr int OFF_KNN    = OFF_ASSIGN + NPTS * KC;    // 327680
constexpr int OFF_STATS  = OFF_KNN + NPTS * NNB;      // 368640
constexpr int OFF_LOSS   = OFF_STATS + NPTS * 3;      // 393216 (loss, intra, inter)

// Workspace layout (float offsets)
constexpr int WS_CNORM = 0;            // 8
constexpr int WS_INTER = 8;            // 1
constexpr int WS_XX    = 16;           // 8192 row norms
constexpr int WS_INTRA = 16 + NPTS;    // 512 block partials
constexpr int WS_CAND  = 16 + NPTS + 512; // float2[NPTS][40] candidates (key, idx)

__device__ __forceinline__ float waveAllSum(float v) {
#pragma unroll
  for (int m = 1; m < 64; m <<= 1) v += __shfl_xor(v, m);
  return v;
}
__device__ __forceinline__ float waveAllMax(float v) {
#pragma unroll
  for (int m = 1; m < 64; m <<= 1) v = fmaxf(v, __shfl_xor(v, m));
  return v;
}

// ---------------- k_init: center norms + inter-cluster distance ----------------
__global__ void k_init(const float* __restrict__ cc, float* __restrict__ ws) {
  int t = threadIdx.x;
  if (t < KC) {
    float s = 0.f;
    for (int j = 0; j < DIM; j++) { float v = cc[t * DIM + j]; s = fmaf(v, v, s); }
    ws[WS_CNORM + t] = s;
  }
  __syncthreads();
  int i = t >> 3, j = t & 7;
  float dot = 0.f;
  for (int u = 0; u < DIM; u++) dot = fmaf(cc[i * DIM + u], cc[j * DIM + u], dot);
  float d2 = ws[WS_CNORM + i] + ws[WS_CNORM + j] - 2.f * dot;
  float d = d2 > 0.f ? sqrtf(d2) : 0.f;
  float v = (i != j) ? d : 0.f;
  v = waveAllSum(v);
  if (t == 0) ws[WS_INTER] = v / 56.f;
}

// ---------------- k_stats: row stats + soft assignment + intra partials --------
__global__ __launch_bounds__(256) void k_stats(
    const float* __restrict__ x, const float* __restrict__ cc,
    const float* __restrict__ temp, const float* __restrict__ cw,
    float* __restrict__ out, float* __restrict__ ws) {
  __shared__ __align__(16) float Cs[KC * DIM];
  __shared__ float cns[KC], cwS[KC];
  __shared__ float intraS[4];
  int tid = threadIdx.x;
  for (int i = tid * 4; i < KC * DIM; i += 1024)
    *(float4*)&Cs[i] = *(const float4*)&cc[i];
  if (tid < KC) { cns[tid] = ws[WS_CNORM + tid]; cwS[tid] = cw[tid]; }
  __syncthreads();
  float T = temp[0];
  int w = tid >> 6, l = tid & 63;
  float intra_acc = 0.f;
  for (int q = 0; q < 4; q++) {
    int row = blockIdx.x * 16 + w * 4 + q;
    float4 v0 = *(const float4*)&x[row * DIM + l * 4];
    float4 v1 = *(const float4*)&x[row * DIM + 256 + l * 4];
    float xv[8] = {v0.x, v0.y, v0.z, v0.w, v1.x, v1.y, v1.z, v1.w};
    float s1 = 0.f, s2 = 0.f, mx = -3e38f;
#pragma unroll
    for (int u = 0; u < 8; u++) { s1 += xv[u]; s2 = fmaf(xv[u], xv[u], s2); mx = fmaxf(mx, xv[u]); }
    s1 = waveAllSum(s1); s2 = waveAllSum(s2); mx = waveAllMax(mx);
    float e = 0.f, ex = 0.f;
#pragma unroll
    for (int u = 0; u < 8; u++) { float p = expf(xv[u] - mx); e += p; ex = fmaf(xv[u], p, ex); }
    e = waveAllSum(e); ex = waveAllSum(ex);
    float dk[KC];
#pragma unroll
    for (int k = 0; k < KC; k++) {
      float4 c0 = *(const float4*)&Cs[k * DIM + l * 4];
      float4 c1 = *(const float4*)&Cs[k * DIM + 256 + l * 4];
      float d = v0.x * c0.x + v0.y * c0.y + v0.z * c0.z + v0.w * c0.w
              + v1.x * c1.x + v1.y * c1.y + v1.z * c1.z + v1.w * c1.w;
      dk[k] = waveAllSum(d);
    }
    float mu = s1 / 512.f;
    float var = (s2 - 512.f * mu * mu) / 511.f;
    if (var < 0.f) var = 0.f;
    float sd = sqrtf(var) + 1e-8f;
    float lse = mx + logf(e);
    float ent = lse - ex / e;
    float dcv[KC], am = -3e38f;
#pragma unroll
    for (int k = 0; k < KC; k++) {
      float d2 = s2 + cns[k] - 2.f * dk[k];
      dcv[k] = d2 > 0.f ? sqrtf(d2) : 0.f;
      am = fmaxf(am, -dcv[k] / T);
    }
    float psum = 0.f, pv[KC];
#pragma unroll
    for (int k = 0; k < KC; k++) { pv[k] = expf(-dcv[k] / T - am); psum += pv[k]; }
    float il = 0.f, asg[KC];
#pragma unroll
    for (int k = 0; k < KC; k++) { asg[k] = pv[k] / psum * cwS[k]; il = fmaf(dcv[k], asg[k], il); }
    intra_acc += il;
    if (l == 0) {
      ws[WS_XX + row] = s2;
      out[OFF_STATS + row * 3 + 0] = mu;
      out[OFF_STATS + row * 3 + 1] = sd;
      out[OFF_STATS + row * 3 + 2] = ent;
#pragma unroll
      for (int k = 0; k < KC; k++) out[OFF_ASSIGN + row * KC + k] = asg[k];
    }
  }
  if (l == 0) intraS[w] = intra_acc;
  __syncthreads();
  if (tid == 0)
    ws[WS_INTRA + blockIdx.x] = intraS[0] + intraS[1] + intraS[2] + intraS[3];
}

// ---------------- k_final: scalar loss outputs ----------------
__global__ void k_final(float* __restrict__ out, const float* __restrict__ ws) {
  __shared__ float ps[4];
  int t = threadIdx.x;
  float v = ws[WS_INTRA + t] + ws[WS_INTRA + t + 256];
  v = waveAllSum(v);
  if ((t & 63) == 0) ps[t >> 6] = v;
  __syncthreads();
  if (t == 0) {
    float intra = (ps[0] + ps[1] + ps[2] + ps[3]) / (8192.f * 8.f);
    float inter = ws[WS_INTER];
    out[OFF_LOSS + 0] = intra - 0.1f * inter;
    out[OFF_LOSS + 1] = intra;
    out[OFF_LOSS + 2] = inter;
  }
}

// ---------------- k_gemm: pairwise distances fused with noisy top-5 -----------
// grid (64, 8): 128-row tile x 1024-col chunk. Per block: 8 col tiles of 128.
__global__ __launch_bounds__(256, 2) void k_gemm(
    const float* __restrict__ x, const float* __restrict__ noise,
    float* __restrict__ ws) {
  __shared__ __align__(16) float As[16][132];
  __shared__ __align__(16) float Bs[16][132];
  __shared__ float xxc[1024];
  const int tid = threadIdx.x;
  const int tx = tid & 7, ty = tid >> 3;
  const int rowbase = blockIdx.x * 128;
  const int colbase = blockIdx.y * 1024;
  const float* xxg = ws + WS_XX;

  for (int i = tid; i < 1024; i += 256) xxc[i] = xxg[colbase + i];
  float xxr[4];
#pragma unroll
  for (int r = 0; r < 4; r++) xxr[r] = xxg[rowbase + ty * 4 + r];

  float k5[4][5]; int i5[4][5];
#pragma unroll
  for (int r = 0; r < 4; r++)
#pragma unroll
    for (int s = 0; s < 5; s++) { k5[r][s] = 3e38f; i5[r][s] = -1; }

  const int rlo = tid >> 2, kq = tid & 3;

  for (int ct = 0; ct < 8; ct++) {
    const int colt = colbase + ct * 128;
    float acc[4][16];
#pragma unroll
    for (int r = 0; r < 4; r++)
#pragma unroll
      for (int c = 0; c < 16; c++) acc[r][c] = 0.f;

    for (int kk = 0; kk < 512; kk += 16) {
      __syncthreads();
      float4 a0 = *(const float4*)&x[(rowbase + rlo) * DIM + kk + kq * 4];
      float4 a1 = *(const float4*)&x[(rowbase + rlo + 64) * DIM + kk + kq * 4];
      float4 b0 = *(const float4*)&x[(colt + rlo) * DIM + kk + kq * 4];
      float4 b1 = *(const float4*)&x[(colt + rlo + 64) * DIM + kk + kq * 4];
      As[kq * 4 + 0][rlo] = a0.x; As[kq * 4 + 1][rlo] = a0.y;
      As[kq * 4 + 2][rlo] = a0.z; As[kq * 4 + 3][rlo] = a0.w;
      As[kq * 4 + 0][rlo + 64] = a1.x; As[kq * 4 + 1][rlo + 64] = a1.y;
      As[kq * 4 + 2][rlo + 64] = a1.z; As[kq * 4 + 3][rlo + 64] = a1.w;
      Bs[kq * 4 + 0][rlo] = b0.x; Bs[kq * 4 + 1][rlo] = b0.y;
      Bs[kq * 4 + 2][rlo] = b0.z; Bs[kq * 4 + 3][rlo] = b0.w;
      Bs[kq * 4 + 0][rlo + 64] = b1.x; Bs[kq * 4 + 1][rlo + 64] = b1.y;
      Bs[kq * 4 + 2][rlo + 64] = b1.z; Bs[kq * 4 + 3][rlo + 64] = b1.w;
      __syncthreads();
#pragma unroll
      for (int k = 0; k < 16; k++) {
        float4 av = *(const float4*)&As[k][ty * 4];
        float a_[4] = {av.x, av.y, av.z, av.w};
#pragma unroll
        for (int j = 0; j < 4; j++) {
          float4 bv = *(const float4*)&Bs[k][tx * 4 + j * 32];
          float b_[4] = {bv.x, bv.y, bv.z, bv.w};
#pragma unroll
          for (int rr = 0; rr < 4; rr++)
#pragma unroll
            for (int uu = 0; uu < 4; uu++)
              acc[rr][j * 4 + uu] = fmaf(a_[rr], b_[uu], acc[rr][j * 4 + uu]);
        }
      }
    }
    // Epilogue: distances + noisy top-5 insertion
#pragma unroll
    for (int r = 0; r < 4; r++) {
      const int row = rowbase + ty * 4 + r;
#pragma unroll
      for (int j = 0; j < 4; j++) {
        const int cl = tx * 4 + j * 32;
        const int col = colt + cl;
        const float4 nz = *(const float4*)&noise[(size_t)row * NPTS + col];
        float nzv[4] = {nz.x, nz.y, nz.z, nz.w};
#pragma unroll
        for (int u = 0; u < 4; u++) {
          float d2 = xxr[r] + xxc[ct * 128 + cl + u] - 2.f * acc[r][j * 4 + u];
          float d = d2 > 0.f ? sqrtf(d2) : 0.f;
          float key = d + 1e-6f * nzv[u];
          int c = col + u;
          if (c != row && key < k5[r][4]) {
            float a = key; int b = c;
#pragma unroll
            for (int s = 0; s < 5; s++) {
              if (a < k5[r][s]) {
                float tf = k5[r][s]; k5[r][s] = a; a = tf;
                int ti = i5[r][s]; i5[r][s] = b; b = ti;
              }
            }
          }
        }
      }
    }
  }

  // Cross-lane merge within each row group (8 lanes share a row) -> 5 winners
#pragma unroll
  for (int r = 0; r < 4; r++) {
    const int row = rowbase + ty * 4 + r;
    float lk[5]; int li[5];
#pragma unroll
    for (int s = 0; s < 5; s++) { lk[s] = k5[r][s]; li[s] = i5[r][s]; }
    float ok[5]; int oi[5];
#pragma unroll
    for (int s = 0; s < 5; s++) {
      float wk = lk[0]; int wi = li[0];
#pragma unroll
      for (int m = 1; m < 8; m <<= 1) {
        float k2 = __shfl_xor(wk, m); int i2 = __shfl_xor(wi, m);
        if (k2 < wk || (k2 == wk && (unsigned)i2 < (unsigned)wi)) { wk = k2; wi = i2; }
      }
      ok[s] = wk; oi[s] = wi;
      if (li[0] == wi && lk[0] == wk) {
        lk[0] = lk[1]; li[0] = li[1];
        lk[1] = lk[2]; li[1] = li[2];
        lk[2] = lk[3]; li[2] = li[3];
        lk[3] = lk[4]; li[3] = li[4];
        lk[4] = 3e38f; li[4] = -1;
      }
    }
    if (tx == 0) {
      float2* cand = (float2*)(ws + WS_CAND);
#pragma unroll
      for (int s = 0; s < 5; s++)
        cand[(size_t)row * 40 + blockIdx.y * 5 + s] =
            make_float2(ok[s], __int_as_float(oi[s]));
    }
  }
}

// ---------------- k_merge: final top-5 + feats + MLP ----------------
__global__ __launch_bounds__(256) void k_merge(
    const float* __restrict__ noise, const float* __restrict__ w1,
    const float* __restrict__ b1, const float* __restrict__ w2,
    const float* __restrict__ b2, float* __restrict__ out,
    const float* __restrict__ ws) {
  __shared__ float w1s[16 * 64];
  __shared__ float b1s[64];
  __shared__ float w2s[64 * 32];
  __shared__ float b2s[32];
  __shared__ float featsS[4][16];
  __shared__ float hS[4][64];
  int tid = threadIdx.x;
  for (int i = tid; i < 1024; i += 256) w1s[i] = w1[i];
  for (int i = tid; i < 2048; i += 256) w2s[i] = w2[i];
  if (tid < 64) b1s[tid] = b1[tid];
  if (tid < 32) b2s[tid] = b2[tid];
  __syncthreads();
  int w = tid >> 6, l = tid & 63;
  const float2* cand = (const float2*)(ws + WS_CAND);
  for (int q = 0; q < 8; q++) {
    int row = blockIdx.x * 32 + w * 8 + q;
    float mk = 3e38f; int mi = -1;
    if (l < 40) {
      float2 c = cand[(size_t)row * 40 + l];
      mk = c.x; mi = __float_as_int(c.y);
    }
#pragma unroll
    for (int s = 0; s < 5; s++) {
      float wk = mk; int wi = mi;
#pragma unroll
      for (int m = 1; m < 64; m <<= 1) {
        float k2 = __shfl_xor(wk, m); int i2 = __shfl_xor(wi, m);
        if (k2 < wk || (k2 == wk && (unsigned)i2 < (unsigned)wi)) { wk = k2; wi = i2; }
      }
      if (mi == wi && mk == wk) mk = 3e38f;  // remove winner from my slot
      if (l == s) {
        float nv = noise[(size_t)row * NPTS + wi];
        float dclean = wk - 1e-6f * nv;
        out[OFF_KNN + row * NNB + s] = dclean;
        featsS[w][8 + s] = dclean;
      }
    }
    if (l < 8) featsS[w][l] = out[OFF_ASSIGN + row * KC + l];
    if (l >= 13 && l < 16) featsS[w][l] = out[OFF_STATS + row * 3 + (l - 13)];
    __syncthreads();
    float h = b1s[l];
#pragma unroll
    for (int i = 0; i < 16; i++) h = fmaf(featsS[w][i], w1s[i * 64 + l], h);
    hS[w][l] = fmaxf(h, 0.f);
    __syncthreads();
    if (l < 32) {
      float e = b2s[l];
#pragma unroll
      for (int i = 0; i < 64; i++) e = fmaf(hS[w][i], w2s[i * 32 + l], e);
      out[OFF_ENC + row * 32 + l] = e;
    }
    __syncthreads();
  }
}

extern "C" void kernel_launch(void* const* d_in, const int* in_sizes, int n_in,
                              void* d_out, int out_size, void* d_ws, size_t ws_size,
                              hipStream_t stream) {
  const float* x     = (const float*)d_in[0];
  const float* noise = (const float*)d_in[1];
  const float* cc    = (const float*)d_in[2];
  const float* w1    = (const float*)d_in[3];
  const float* b1    = (const float*)d_in[4];
  const float* w2    = (const float*)d_in[5];
  const float* b2    = (const float*)d_in[6];
  const float* temp  = (const float*)d_in[7];
  const float* cw    = (const float*)d_in[8];
  float* out = (float*)d_out;
  float* ws  = (float*)d_ws;

  hipLaunchKernelGGL(k_init,  dim3(1),       dim3(64),  0, stream, cc, ws);
  hipLaunchKernelGGL(k_stats, dim3(512),     dim3(256), 0, stream, x, cc, temp, cw, out, ws);
  hipLaunchKernelGGL(k_final, dim3(1),       dim3(256), 0, stream, out, ws);
  hipLaunchKernelGGL(k_gemm,  dim3(64, 8),   dim3(256), 0, stream, x, noise, ws);
  hipLaunchKernelGGL(k_merge, dim3(256),     dim3(256), 0, stream, noise, w1, b1, w2, b2, out, ws);
}

// Round 2
// 363.545 us; speedup vs baseline: 2.9936x; 2.9936x over previous
//
#include <hip/hip_runtime.h>
#include <math.h>

// Problem sizes
constexpr int NPTS = 8192;
constexpr int DIM  = 512;
constexpr int KC   = 8;    // clusters
constexpr int NNB  = 5;    // neighbors

// Output layout (floats)
constexpr int OFF_ENC    = 0;
constexpr int OFF_ASSIGN = NPTS * 32;                 // 262144
constexpr int OFF_KNN    = OFF_ASSIGN + NPTS * KC;    // 327680
constexpr int OFF_STATS  = OFF_KNN + NPTS * NNB;      // 368640
constexpr int OFF_LOSS   = OFF_STATS + NPTS * 3;      // 393216 (loss, intra, inter)

// Workspace layout (float offsets)
constexpr int WS_CNORM = 0;            // 8
constexpr int WS_INTER = 8;            // 1
constexpr int WS_XX    = 16;           // 8192 row norms
constexpr int WS_INTRA = 16 + NPTS;    // 512 block partials
constexpr int WS_CAND  = 16 + NPTS + 512; // float2[NPTS][40] candidates (key, idx)
constexpr size_t XB_OFF = 4u << 20;    // byte offset of bf16 copy of x (8192*512*2 = 8 MB)

typedef short bf16x8 __attribute__((ext_vector_type(8)));
typedef float f32x16 __attribute__((ext_vector_type(16)));

__device__ __forceinline__ float waveAllSum(float v) {
#pragma unroll
  for (int m = 1; m < 64; m <<= 1) v += __shfl_xor(v, m);
  return v;
}
__device__ __forceinline__ float waveAllMax(float v) {
#pragma unroll
  for (int m = 1; m < 64; m <<= 1) v = fmaxf(v, __shfl_xor(v, m));
  return v;
}

__device__ __forceinline__ unsigned short f2bf(float f) {
  unsigned u = __float_as_uint(f);
  unsigned r = (u + 0x7FFFu + ((u >> 16) & 1u)) >> 16;  // RNE
  return (unsigned short)r;
}

// async global(16B/lane) -> LDS, linear dest (wave-uniform base + lane*16)
__device__ __forceinline__ void gload16(const void* g, void* lds) {
  __builtin_amdgcn_global_load_lds(
      (const __attribute__((address_space(1))) unsigned int*)(unsigned long long)g,
      (__attribute__((address_space(3))) unsigned int*)(unsigned)(unsigned long long)lds,
      16, 0, 0);
}

// ---------------- k_init: center norms + inter-cluster distance ----------------
__global__ void k_init(const float* __restrict__ cc, float* __restrict__ ws) {
  int t = threadIdx.x;
  if (t < KC) {
    float s = 0.f;
    for (int j = 0; j < DIM; j++) { float v = cc[t * DIM + j]; s = fmaf(v, v, s); }
    ws[WS_CNORM + t] = s;
  }
  __syncthreads();
  int i = t >> 3, j = t & 7;
  float dot = 0.f;
  for (int u = 0; u < DIM; u++) dot = fmaf(cc[i * DIM + u], cc[j * DIM + u], dot);
  float d2 = ws[WS_CNORM + i] + ws[WS_CNORM + j] - 2.f * dot;
  float d = d2 > 0.f ? sqrtf(d2) : 0.f;
  float v = (i != j) ? d : 0.f;
  v = waveAllSum(v);
  if (t == 0) ws[WS_INTER] = v / 56.f;
}

// ---------------- k_stats: row stats + soft assignment + intra partials --------
__global__ __launch_bounds__(256) void k_stats(
    const float* __restrict__ x, const float* __restrict__ cc,
    const float* __restrict__ temp, const float* __restrict__ cw,
    float* __restrict__ out, float* __restrict__ ws) {
  __shared__ __align__(16) float Cs[KC * DIM];
  __shared__ float cns[KC], cwS[KC];
  __shared__ float intraS[4];
  int tid = threadIdx.x;
  for (int i = tid * 4; i < KC * DIM; i += 1024)
    *(float4*)&Cs[i] = *(const float4*)&cc[i];
  if (tid < KC) { cns[tid] = ws[WS_CNORM + tid]; cwS[tid] = cw[tid]; }
  __syncthreads();
  float T = temp[0];
  int w = tid >> 6, l = tid & 63;
  float intra_acc = 0.f;
  for (int q = 0; q < 4; q++) {
    int row = blockIdx.x * 16 + w * 4 + q;
    float4 v0 = *(const float4*)&x[row * DIM + l * 4];
    float4 v1 = *(const float4*)&x[row * DIM + 256 + l * 4];
    float xv[8] = {v0.x, v0.y, v0.z, v0.w, v1.x, v1.y, v1.z, v1.w};
    float s1 = 0.f, s2 = 0.f, mx = -3e38f;
#pragma unroll
    for (int u = 0; u < 8; u++) { s1 += xv[u]; s2 = fmaf(xv[u], xv[u], s2); mx = fmaxf(mx, xv[u]); }
    s1 = waveAllSum(s1); s2 = waveAllSum(s2); mx = waveAllMax(mx);
    float e = 0.f, ex = 0.f;
#pragma unroll
    for (int u = 0; u < 8; u++) { float p = expf(xv[u] - mx); e += p; ex = fmaf(xv[u], p, ex); }
    e = waveAllSum(e); ex = waveAllSum(ex);
    float dk[KC];
#pragma unroll
    for (int k = 0; k < KC; k++) {
      float4 c0 = *(const float4*)&Cs[k * DIM + l * 4];
      float4 c1 = *(const float4*)&Cs[k * DIM + 256 + l * 4];
      float d = v0.x * c0.x + v0.y * c0.y + v0.z * c0.z + v0.w * c0.w
              + v1.x * c1.x + v1.y * c1.y + v1.z * c1.z + v1.w * c1.w;
      dk[k] = waveAllSum(d);
    }
    float mu = s1 / 512.f;
    float var = (s2 - 512.f * mu * mu) / 511.f;
    if (var < 0.f) var = 0.f;
    float sd = sqrtf(var) + 1e-8f;
    float lse = mx + logf(e);
    float ent = lse - ex / e;
    float dcv[KC], am = -3e38f;
#pragma unroll
    for (int k = 0; k < KC; k++) {
      float d2 = s2 + cns[k] - 2.f * dk[k];
      dcv[k] = d2 > 0.f ? sqrtf(d2) : 0.f;
      am = fmaxf(am, -dcv[k] / T);
    }
    float psum = 0.f, pv[KC];
#pragma unroll
    for (int k = 0; k < KC; k++) { pv[k] = expf(-dcv[k] / T - am); psum += pv[k]; }
    float il = 0.f, asg[KC];
#pragma unroll
    for (int k = 0; k < KC; k++) { asg[k] = pv[k] / psum * cwS[k]; il = fmaf(dcv[k], asg[k], il); }
    intra_acc += il;
    if (l == 0) {
      ws[WS_XX + row] = s2;
      out[OFF_STATS + row * 3 + 0] = mu;
      out[OFF_STATS + row * 3 + 1] = sd;
      out[OFF_STATS + row * 3 + 2] = ent;
#pragma unroll
      for (int k = 0; k < KC; k++) out[OFF_ASSIGN + row * KC + k] = asg[k];
    }
  }
  if (l == 0) intraS[w] = intra_acc;
  __syncthreads();
  if (tid == 0)
    ws[WS_INTRA + blockIdx.x] = intraS[0] + intraS[1] + intraS[2] + intraS[3];
}

// ---------------- k_final: scalar loss outputs ----------------
__global__ void k_final(float* __restrict__ out, const float* __restrict__ ws) {
  __shared__ float ps[4];
  int t = threadIdx.x;
  float v = ws[WS_INTRA + t] + ws[WS_INTRA + t + 256];
  v = waveAllSum(v);
  if ((t & 63) == 0) ps[t >> 6] = v;
  __syncthreads();
  if (t == 0) {
    float intra = (ps[0] + ps[1] + ps[2] + ps[3]) / (8192.f * 8.f);
    float inter = ws[WS_INTER];
    out[OFF_LOSS + 0] = intra - 0.1f * inter;
    out[OFF_LOSS + 1] = intra;
    out[OFF_LOSS + 2] = inter;
  }
}

// ---------------- k_cvt: x f32 -> bf16 (RNE) ----------------
__global__ __launch_bounds__(256) void k_cvt(const float* __restrict__ x,
                                             unsigned short* __restrict__ xb) {
  int i = (blockIdx.x * 256 + threadIdx.x) * 8;
  float4 v0 = *(const float4*)&x[i];
  float4 v1 = *(const float4*)&x[i + 4];
  bf16x8 o;
  o[0] = (short)f2bf(v0.x); o[1] = (short)f2bf(v0.y);
  o[2] = (short)f2bf(v0.z); o[3] = (short)f2bf(v0.w);
  o[4] = (short)f2bf(v1.x); o[5] = (short)f2bf(v1.y);
  o[6] = (short)f2bf(v1.z); o[7] = (short)f2bf(v1.w);
  *(bf16x8*)&xb[i] = o;
}

// ---------------- k_gemm2: MFMA pairwise distances + fused noisy top-5 --------
// grid (64, 8): 128-row tile x 1024-col chunk (8 col-tiles of 128 per block).
// 4 waves as 2x2; wave tile 64x64 = 2x2 frags of mfma_f32_32x32x16_bf16. BK=64.
// LDS: As/Bs (16KB each, XOR-swizzled slots) union'd with transpose buffer Tb.

// top-5 insert (strict <, earlier/lower idx wins ties)
#define INS5(P, KEY, IDX)                                                        \
  { float a_ = (KEY); int b_ = (IDX);                                            \
    if (a_ < k##P##0) { float t_=k##P##0; k##P##0=a_; a_=t_; int u_=i##P##0; i##P##0=b_; b_=u_; } \
    if (a_ < k##P##1) { float t_=k##P##1; k##P##1=a_; a_=t_; int u_=i##P##1; i##P##1=b_; b_=u_; } \
    if (a_ < k##P##2) { float t_=k##P##2; k##P##2=a_; a_=t_; int u_=i##P##2; i##P##2=b_; b_=u_; } \
    if (a_ < k##P##3) { float t_=k##P##3; k##P##3=a_; a_=t_; int u_=i##P##3; i##P##3=b_; b_=u_; } \
    if (a_ < k##P##4) { float t_=k##P##4; k##P##4=a_; a_=t_; int u_=i##P##4; i##P##4=b_; b_=u_; } \
    float t5_ = k##P##4 + 8e-6f; t2##P = t5_ * t5_; }

#define PROC(P, DOT, XC, COL, ROW, XR, NROW)                                     \
  { float d2_ = (XR) + (XC) - 2.0f * (DOT);                                      \
    if (d2_ < t2##P) {                                                           \
      float d_ = sqrtf(fmaxf(d2_, 0.0f));                                        \
      int c_ = (COL);                                                            \
      if (c_ != (ROW)) {                                                         \
        float key_ = fmaf(1e-6f, (NROW)[c_], d_);                                \
        if (key_ < k##P##4) { INS5(P, key_, c_) }                                \
      } } }

#define MERGE5(P, ROW)                                                           \
  { float m0=k##P##0,m1=k##P##1,m2=k##P##2,m3=k##P##3,m4=k##P##4;                \
    int   n0=i##P##0,n1=i##P##1,n2=i##P##2,n3=i##P##3,n4=i##P##4;                \
    for (int s_ = 0; s_ < 5; s_++) {                                             \
      float wk = m0; int wi = n0;                                                \
      float q_ = __shfl_xor(wk, 1); int j_ = __shfl_xor(wi, 1);                  \
      if (q_ < wk || (q_ == wk && (unsigned)j_ < (unsigned)wi)) { wk=q_; wi=j_; }\
      q_ = __shfl_xor(wk, 2); j_ = __shfl_xor(wi, 2);                            \
      if (q_ < wk || (q_ == wk && (unsigned)j_ < (unsigned)wi)) { wk=q_; wi=j_; }\
      if (m0 == wk && n0 == wi) { m0=m1;n0=n1; m1=m2;n1=n2; m2=m3;n2=n3; m3=m4;n3=n4; m4=3e38f;n4=-1; } \
      if ((tid & 3) == 0)                                                        \
        candp[(size_t)(ROW) * 40 + blockIdx.y * 5 + s_] = make_float2(wk, __int_as_float(wi)); \
    } }

__global__ __launch_bounds__(256) void k_gemm2(
    const unsigned short* __restrict__ xb, const float* __restrict__ noise,
    float* __restrict__ ws) {
  __shared__ __align__(16) char SMEM[64 * 132 * 4];  // 33792 B: As(16K)+Bs(16K) U Tb[64][132]f32
  __shared__ float xxc[1024];
  const int tid = threadIdx.x;
  const int l = tid & 63, w = tid >> 6;
  const int wr = w >> 1, wc = w & 1;
  const int rowbase = blockIdx.x * 128;
  const int colbase = blockIdx.y * 1024;
  const float* xxg = ws + WS_XX;
  float2* candp = (float2*)(ws + WS_CAND);

  for (int i = tid; i < 1024; i += 256) xxc[i] = xxg[colbase + i];

  // epilogue reader assignment: 4 threads/row-slot, 32 cols each
  const int slot = tid >> 2, seg = tid & 3;
  const int rowA = rowbase + (slot >> 5) * 64 + (slot & 31);  // pass m=0
  const int rowB = rowA + 32;                                  // pass m=1
  const float xxrA = xxg[rowA], xxrB = xxg[rowB];
  const float* nrowA = noise + (size_t)rowA * NPTS;
  const float* nrowB = noise + (size_t)rowB * NPTS;

  // staging lane decomposition: 8 rows x 8 slots per 1KB instruction
  const int srow = l >> 3;          // row within 8-row chunk
  const int sg   = (l & 7) ^ srow;  // pre-swizzled k-group (slot ^ row&7)

  // fragment read bases (bytes)
  const int rAb = ((wr << 6) + (l & 31)) << 7;            // A rows
  const int rBb = 16384 + (((wc << 6) + (l & 31)) << 7);  // B col-rows
  const int l7 = l & 7, lh = l >> 5;

  // persistent per-thread top-5 state (noisy keys), two passes
  float ka0=3e38f,ka1=3e38f,ka2=3e38f,ka3=3e38f,ka4=3e38f;
  float kb0=3e38f,kb1=3e38f,kb2=3e38f,kb3=3e38f,kb4=3e38f;
  int   ia0=-1,ia1=-1,ia2=-1,ia3=-1,ia4=-1;
  int   ib0=-1,ib1=-1,ib2=-1,ib3=-1,ib4=-1;
  float t2a = 3e38f, t2b = 3e38f;

  for (int ct = 0; ct < 8; ct++) {
    const int colt = colbase + ct * 128;
    f32x16 acc00 = {0}, acc01 = {0}, acc10 = {0}, acc11 = {0};

    for (int ks = 0; ks < 8; ks++) {
      __syncthreads();  // previous-phase LDS consumers done
      const int ke = ks << 6;
#pragma unroll
      for (int jj = 0; jj < 4; jj++) {
        const int rloc = w * 32 + jj * 8 + srow;
        const unsigned short* srcA = xb + (size_t)(rowbase + rloc) * DIM + ke + sg * 8;
        gload16(srcA, SMEM + (w * 4 + jj) * 1024);
        const unsigned short* srcB = xb + (size_t)(colt + rloc) * DIM + ke + sg * 8;
        gload16(srcB, SMEM + 16384 + (w * 4 + jj) * 1024);
      }
      __syncthreads();  // compiler drains vmcnt(0) before barrier
#pragma unroll
      for (int kk = 0; kk < 4; kk++) {
        const int offk = ((lh + 2 * kk) ^ l7) << 4;
        bf16x8 a0 = *(const bf16x8*)(SMEM + rAb + offk);
        bf16x8 a1 = *(const bf16x8*)(SMEM + rAb + 4096 + offk);
        bf16x8 b0 = *(const bf16x8*)(SMEM + rBb + offk);
        bf16x8 b1 = *(const bf16x8*)(SMEM + rBb + 4096 + offk);
        acc00 = __builtin_amdgcn_mfma_f32_32x32x16_bf16(a0, b0, acc00, 0, 0, 0);
        acc01 = __builtin_amdgcn_mfma_f32_32x32x16_bf16(a0, b1, acc01, 0, 0, 0);
        acc10 = __builtin_amdgcn_mfma_f32_32x32x16_bf16(a1, b0, acc10, 0, 0, 0);
        acc11 = __builtin_amdgcn_mfma_f32_32x32x16_bf16(a1, b1, acc11, 0, 0, 0);
      }
    }

    float* Tb = (float*)SMEM;
    // ---- pass 0 (rows m=0): transpose acc00/acc01 through LDS ----
    __syncthreads();
#pragma unroll
    for (int r = 0; r < 16; r++) {
      const int sl = (wr << 5) + (lh << 2) + (r & 3) + ((r >> 2) << 3);
      const int cL = (wc << 6) + (l & 31);
      Tb[sl * 132 + cL]      = acc00[r];
      Tb[sl * 132 + cL + 32] = acc01[r];
    }
    __syncthreads();
#pragma unroll
    for (int i8 = 0; i8 < 8; i8++) {
      const int cl = seg * 32 + i8 * 4;
      const float4 dv = *(const float4*)&Tb[slot * 132 + cl];
      const float4 xq = *(const float4*)&xxc[ct * 128 + cl];
      PROC(a, dv.x, xq.x, colt + cl + 0, rowA, xxrA, nrowA)
      PROC(a, dv.y, xq.y, colt + cl + 1, rowA, xxrA, nrowA)
      PROC(a, dv.z, xq.z, colt + cl + 2, rowA, xxrA, nrowA)
      PROC(a, dv.w, xq.w, colt + cl + 3, rowA, xxrA, nrowA)
    }
    // ---- pass 1 (rows m=1): acc10/acc11 ----
    __syncthreads();
#pragma unroll
    for (int r = 0; r < 16; r++) {
      const int sl = (wr << 5) + (lh << 2) + (r & 3) + ((r >> 2) << 3);
      const int cL = (wc << 6) + (l & 31);
      Tb[sl * 132 + cL]      = acc10[r];
      Tb[sl * 132 + cL + 32] = acc11[r];
    }
    __syncthreads();
#pragma unroll
    for (int i8 = 0; i8 < 8; i8++) {
      const int cl = seg * 32 + i8 * 4;
      const float4 dv = *(const float4*)&Tb[slot * 132 + cl];
      const float4 xq = *(const float4*)&xxc[ct * 128 + cl];
      PROC(b, dv.x, xq.x, colt + cl + 0, rowB, xxrB, nrowB)
      PROC(b, dv.y, xq.y, colt + cl + 1, rowB, xxrB, nrowB)
      PROC(b, dv.z, xq.z, colt + cl + 2, rowB, xxrB, nrowB)
      PROC(b, dv.w, xq.w, colt + cl + 3, rowB, xxrB, nrowB)
    }
  }

  // final 4-thread merge per row, write 5 candidates per row per chunk
  MERGE5(a, rowA)
  MERGE5(b, rowB)
}

// ---------------- k_gemm (fallback, fp32 VALU): unchanged from round 1 --------
__global__ __launch_bounds__(256, 2) void k_gemm(
    const float* __restrict__ x, const float* __restrict__ noise,
    float* __restrict__ ws) {
  __shared__ __align__(16) float As[16][132];
  __shared__ __align__(16) float Bs[16][132];
  __shared__ float xxc[1024];
  const int tid = threadIdx.x;
  const int tx = tid & 7, ty = tid >> 3;
  const int rowbase = blockIdx.x * 128;
  const int colbase = blockIdx.y * 1024;
  const float* xxg = ws + WS_XX;

  for (int i = tid; i < 1024; i += 256) xxc[i] = xxg[colbase + i];
  float xxr[4];
#pragma unroll
  for (int r = 0; r < 4; r++) xxr[r] = xxg[rowbase + ty * 4 + r];

  float k5[4][5]; int i5[4][5];
#pragma unroll
  for (int r = 0; r < 4; r++)
#pragma unroll
    for (int s = 0; s < 5; s++) { k5[r][s] = 3e38f; i5[r][s] = -1; }

  const int rlo = tid >> 2, kq = tid & 3;

  for (int ct = 0; ct < 8; ct++) {
    const int colt = colbase + ct * 128;
    float acc[4][16];
#pragma unroll
    for (int r = 0; r < 4; r++)
#pragma unroll
      for (int c = 0; c < 16; c++) acc[r][c] = 0.f;

    for (int kk = 0; kk < 512; kk += 16) {
      __syncthreads();
      float4 a0 = *(const float4*)&x[(rowbase + rlo) * DIM + kk + kq * 4];
      float4 a1 = *(const float4*)&x[(rowbase + rlo + 64) * DIM + kk + kq * 4];
      float4 b0 = *(const float4*)&x[(colt + rlo) * DIM + kk + kq * 4];
      float4 b1 = *(const float4*)&x[(colt + rlo + 64) * DIM + kk + kq * 4];
      As[kq * 4 + 0][rlo] = a0.x; As[kq * 4 + 1][rlo] = a0.y;
      As[kq * 4 + 2][rlo] = a0.z; As[kq * 4 + 3][rlo] = a0.w;
      As[kq * 4 + 0][rlo + 64] = a1.x; As[kq * 4 + 1][rlo + 64] = a1.y;
      As[kq * 4 + 2][rlo + 64] = a1.z; As[kq * 4 + 3][rlo + 64] = a1.w;
      Bs[kq * 4 + 0][rlo] = b0.x; Bs[kq * 4 + 1][rlo] = b0.y;
      Bs[kq * 4 + 2][rlo] = b0.z; Bs[kq * 4 + 3][rlo] = b0.w;
      Bs[kq * 4 + 0][rlo + 64] = b1.x; Bs[kq * 4 + 1][rlo + 64] = b1.y;
      Bs[kq * 4 + 2][rlo + 64] = b1.z; Bs[kq * 4 + 3][rlo + 64] = b1.w;
      __syncthreads();
#pragma unroll
      for (int k = 0; k < 16; k++) {
        float4 av = *(const float4*)&As[k][ty * 4];
        float a_[4] = {av.x, av.y, av.z, av.w};
#pragma unroll
        for (int j = 0; j < 4; j++) {
          float4 bv = *(const float4*)&Bs[k][tx * 4 + j * 32];
          float b_[4] = {bv.x, bv.y, bv.z, bv.w};
#pragma unroll
          for (int rr = 0; rr < 4; rr++)
#pragma unroll
            for (int uu = 0; uu < 4; uu++)
              acc[rr][j * 4 + uu] = fmaf(a_[rr], b_[uu], acc[rr][j * 4 + uu]);
        }
      }
    }
#pragma unroll
    for (int r = 0; r < 4; r++) {
      const int row = rowbase + ty * 4 + r;
#pragma unroll
      for (int j = 0; j < 4; j++) {
        const int cl = tx * 4 + j * 32;
        const int col = colt + cl;
        const float4 nz = *(const float4*)&noise[(size_t)row * NPTS + col];
        float nzv[4] = {nz.x, nz.y, nz.z, nz.w};
#pragma unroll
        for (int u = 0; u < 4; u++) {
          float d2 = xxr[r] + xxc[ct * 128 + cl + u] - 2.f * acc[r][j * 4 + u];
          float d = d2 > 0.f ? sqrtf(d2) : 0.f;
          float key = d + 1e-6f * nzv[u];
          int c = col + u;
          if (c != row && key < k5[r][4]) {
            float a = key; int b = c;
#pragma unroll
            for (int s = 0; s < 5; s++) {
              if (a < k5[r][s]) {
                float tf = k5[r][s]; k5[r][s] = a; a = tf;
                int ti = i5[r][s]; i5[r][s] = b; b = ti;
              }
            }
          }
        }
      }
    }
  }

#pragma unroll
  for (int r = 0; r < 4; r++) {
    const int row = rowbase + ty * 4 + r;
    float lk[5]; int li[5];
#pragma unroll
    for (int s = 0; s < 5; s++) { lk[s] = k5[r][s]; li[s] = i5[r][s]; }
#pragma unroll
    for (int s = 0; s < 5; s++) {
      float wk = lk[0]; int wi = li[0];
#pragma unroll
      for (int m = 1; m < 8; m <<= 1) {
        float k2 = __shfl_xor(wk, m); int i2 = __shfl_xor(wi, m);
        if (k2 < wk || (k2 == wk && (unsigned)i2 < (unsigned)wi)) { wk = k2; wi = i2; }
      }
      if (li[0] == wi && lk[0] == wk) {
        lk[0] = lk[1]; li[0] = li[1];
        lk[1] = lk[2]; li[1] = li[2];
        lk[2] = lk[3]; li[2] = li[3];
        lk[3] = lk[4]; li[3] = li[4];
        lk[4] = 3e38f; li[4] = -1;
      }
      if (tx == 0) {
        float2* cand = (float2*)(ws + WS_CAND);
        cand[(size_t)row * 40 + blockIdx.y * 5 + s] = make_float2(wk, __int_as_float(wi));
      }
    }
  }
}

// ---------------- k_merge: final top-5 + feats + MLP ----------------
__global__ __launch_bounds__(256) void k_merge(
    const float* __restrict__ noise, const float* __restrict__ w1,
    const float* __restrict__ b1, const float* __restrict__ w2,
    const float* __restrict__ b2, float* __restrict__ out,
    const float* __restrict__ ws) {
  __shared__ float w1s[16 * 64];
  __shared__ float b1s[64];
  __shared__ float w2s[64 * 32];
  __shared__ float b2s[32];
  __shared__ float featsS[4][16];
  __shared__ float hS[4][64];
  int tid = threadIdx.x;
  for (int i = tid; i < 1024; i += 256) w1s[i] = w1[i];
  for (int i = tid; i < 2048; i += 256) w2s[i] = w2[i];
  if (tid < 64) b1s[tid] = b1[tid];
  if (tid < 32) b2s[tid] = b2[tid];
  __syncthreads();
  int w = tid >> 6, l = tid & 63;
  const float2* cand = (const float2*)(ws + WS_CAND);
  for (int q = 0; q < 8; q++) {
    int row = blockIdx.x * 32 + w * 8 + q;
    float mk = 3e38f; int mi = -1;
    if (l < 40) {
      float2 c = cand[(size_t)row * 40 + l];
      mk = c.x; mi = __float_as_int(c.y);
    }
#pragma unroll
    for (int s = 0; s < 5; s++) {
      float wk = mk; int wi = mi;
#pragma unroll
      for (int m = 1; m < 64; m <<= 1) {
        float k2 = __shfl_xor(wk, m); int i2 = __shfl_xor(wi, m);
        if (k2 < wk || (k2 == wk && (unsigned)i2 < (unsigned)wi)) { wk = k2; wi = i2; }
      }
      if (mi == wi && mk == wk) mk = 3e38f;  // remove winner from my slot
      if (l == s) {
        float nv = noise[(size_t)row * NPTS + wi];
        float dclean = wk - 1e-6f * nv;
        out[OFF_KNN + row * NNB + s] = dclean;
        featsS[w][8 + s] = dclean;
      }
    }
    if (l < 8) featsS[w][l] = out[OFF_ASSIGN + row * KC + l];
    if (l >= 13 && l < 16) featsS[w][l] = out[OFF_STATS + row * 3 + (l - 13)];
    __syncthreads();
    float h = b1s[l];
#pragma unroll
    for (int i = 0; i < 16; i++) h = fmaf(featsS[w][i], w1s[i * 64 + l], h);
    hS[w][l] = fmaxf(h, 0.f);
    __syncthreads();
    if (l < 32) {
      float e = b2s[l];
#pragma unroll
      for (int i = 0; i < 64; i++) e = fmaf(hS[w][i], w2s[i * 32 + l], e);
      out[OFF_ENC + row * 32 + l] = e;
    }
    __syncthreads();
  }
}

extern "C" void kernel_launch(void* const* d_in, const int* in_sizes, int n_in,
                              void* d_out, int out_size, void* d_ws, size_t ws_size,
                              hipStream_t stream) {
  const float* x     = (const float*)d_in[0];
  const float* noise = (const float*)d_in[1];
  const float* cc    = (const float*)d_in[2];
  const float* w1    = (const float*)d_in[3];
  const float* b1    = (const float*)d_in[4];
  const float* w2    = (const float*)d_in[5];
  const float* b2    = (const float*)d_in[6];
  const float* temp  = (const float*)d_in[7];
  const float* cw    = (const float*)d_in[8];
  float* out = (float*)d_out;
  float* ws  = (float*)d_ws;

  const size_t need = XB_OFF + (size_t)NPTS * DIM * 2;  // 12.6 MB
  const bool fast = ws_size >= need;

  hipLaunchKernelGGL(k_init,  dim3(1),   dim3(64),  0, stream, cc, ws);
  hipLaunchKernelGGL(k_stats, dim3(512), dim3(256), 0, stream, x, cc, temp, cw, out, ws);
  hipLaunchKernelGGL(k_final, dim3(1),   dim3(256), 0, stream, out, ws);
  if (fast) {
    unsigned short* xb = (unsigned short*)((char*)d_ws + XB_OFF);
    hipLaunchKernelGGL(k_cvt,   dim3(2048),    dim3(256), 0, stream, x, xb);
    hipLaunchKernelGGL(k_gemm2, dim3(64, 8),   dim3(256), 0, stream, xb, noise, ws);
  } else {
    hipLaunchKernelGGL(k_gemm,  dim3(64, 8),   dim3(256), 0, stream, x, noise, ws);
  }
  hipLaunchKernelGGL(k_merge, dim3(256), dim3(256), 0, stream, noise, w1, b1, w2, b2, out, ws);
}